// Round 9
// baseline (228.942 us; speedup 1.0000x reference)
//
#include <hip/hip_runtime.h>
#include <math.h>

#define Hh 128
#define Ww 128
#define Dd 256
#define Bb 4
#define HW (Hh*Ww)        // 16384
#define NPIX (Bb*HW)      // 65536
#define WP 132            // xb padded width/height (2-px zero ring)
#define WP1 136           // h1 padded width/height (4-px zero ring)

typedef __attribute__((ext_vector_type(8))) short s16x8;   // 8 bf16 (4 VGPRs)
typedef __attribute__((ext_vector_type(4))) float f32x4;

__device__ __forceinline__ unsigned short f2bf(float f) {
    unsigned u = __float_as_uint(f);
    u += 0x7FFF + ((u >> 16) & 1);
    return (unsigned short)(u >> 16);
}

__device__ __forceinline__ float gelu_exact(float v) {
    return 0.5f * v * (1.0f + erff(v * 0.70710678118654752f));
}

// ring pixel i in [0,1040) -> (y,x) on the 2-px border of a 132x132 image
__device__ __forceinline__ void ring_yx(int i, int& y, int& x) {
    if (i < 264) { y = i / 132; x = i - y * 132; }
    else if (i < 528) { int j = i - 264; int r = j / 132; y = 130 + r; x = j - r * 132; }
    else { int j = i - 528; y = 2 + (j >> 2); int m = j & 3; x = (m < 2) ? m : 128 + m; }
}

// ring pixel i in [0,2112) -> (y,x) on the 4-px border of a 136x136 image
__device__ __forceinline__ void ring4_yx(int i, int& y, int& x) {
    if (i < 544) { y = i / 136; x = i - y * 136; }
    else if (i < 1088) { int j = i - 544; int r = j / 136; y = 132 + r; x = j - r * 136; }
    else { int j = i - 1088; y = 4 + (j >> 3); int m = j & 7; x = (m < 4) ? m : 128 + m; }
}

// ---------- K0: ring zeros + weight transpose + vis norm (NO LDS) ----------
// kn channel layout per pixel: lane l (of 32) owns ch {l*4..l*4+3, 128+l*4..+3}
// stored contiguously at short offset l*8.
// blocks 0..611    : xb ring (33280 gran) + h1 ring4 (33792 gran) + weights (89600)
// blocks 612..4707 : vis -> kn (32-lane groups, 2 px each)
__global__ __launch_bounds__(256) void setup_norm(const float* __restrict__ w0,
                                                  const float* __restrict__ w1,
                                                  const float* __restrict__ w2,
                                                  unsigned short* __restrict__ wb0,
                                                  unsigned short* __restrict__ wb1,
                                                  unsigned short* __restrict__ wb2,
                                                  unsigned short* __restrict__ xbp,
                                                  unsigned short* __restrict__ h1p,
                                                  const float* __restrict__ vis,
                                                  unsigned short* __restrict__ kn) {
    int tid = threadIdx.x;
    int blk = blockIdx.x;
    if (blk < 612) {
        int t = blk * 256 + tid;
        uint4 z = (uint4){0, 0, 0, 0};
        if (t < 33280) {
            int img = t / 8320; int r = t - img * 8320; int px = r >> 3, g = r & 7;
            int y, x; ring_yx(px, y, x);
            *(uint4*)(xbp + ((size_t)(img * WP + y) * WP + x) * 64 + g * 8) = z;
            return;
        }
        if (t < 67072) {
            int u2 = t - 33280;
            int img = u2 / 8448; int r = u2 - img * 8448; int px = r >> 2, g = r & 3;
            int y, x; ring4_yx(px, y, x);
            *(uint4*)(h1p + ((size_t)(img * WP1 + y) * WP1 + x) * 32 + g * 8) = z;
            return;
        }
        int u = t - 67072;
        if (u < 51200) {
            int tap = u >> 11; int r = u & 2047; int n = r >> 6; int k = r & 63;
            wb0[u] = (k < 52) ? f2bf(w0[n * 1300 + k * 25 + tap]) : (unsigned short)0;
        } else if (u < 76800) {
            int v = u - 51200; int tap = v >> 10; int r = v & 1023; int n = r >> 5; int k = r & 31;
            wb1[v] = f2bf(w1[n * 800 + k * 25 + tap]);
        } else {
            int v = u - 76800; int tap = v >> 9; int r = v & 511; int n = r >> 5; int k = r & 31;
            wb2[v] = (n < 2) ? f2bf(w2[n * 800 + k * 25 + tap]) : (unsigned short)0;
        }
        return;
    }
    int nb = blk - 612;
    int g32 = tid >> 5, l = tid & 31;
    int pix0 = nb * 16 + g32 * 2;
    const float* base0 = vis + (size_t)pix0 * Dd + l * 4;
    float4 a0 = *(const float4*)(base0);
    float4 b0 = *(const float4*)(base0 + 128);
    float4 a1 = *(const float4*)(base0 + 256);
    float4 b1 = *(const float4*)(base0 + 384);
    float ss0 = a0.x * a0.x + a0.y * a0.y + a0.z * a0.z + a0.w * a0.w +
                b0.x * b0.x + b0.y * b0.y + b0.z * b0.z + b0.w * b0.w;
    float ss1 = a1.x * a1.x + a1.y * a1.y + a1.z * a1.z + a1.w * a1.w +
                b1.x * b1.x + b1.y * b1.y + b1.z * b1.z + b1.w * b1.w;
#pragma unroll
    for (int o = 1; o <= 16; o <<= 1) {
        ss0 += __shfl_xor(ss0, o, 64);
        ss1 += __shfl_xor(ss1, o, 64);
    }
    float inv0 = __builtin_amdgcn_rsqf(fmaxf(ss0, 1e-24f));
    float inv1 = __builtin_amdgcn_rsqf(fmaxf(ss1, 1e-24f));
    uint4 o0, o1;
    o0.x = f2bf(a0.x * inv0) | ((unsigned)f2bf(a0.y * inv0) << 16);
    o0.y = f2bf(a0.z * inv0) | ((unsigned)f2bf(a0.w * inv0) << 16);
    o0.z = f2bf(b0.x * inv0) | ((unsigned)f2bf(b0.y * inv0) << 16);
    o0.w = f2bf(b0.z * inv0) | ((unsigned)f2bf(b0.w * inv0) << 16);
    o1.x = f2bf(a1.x * inv1) | ((unsigned)f2bf(a1.y * inv1) << 16);
    o1.y = f2bf(a1.z * inv1) | ((unsigned)f2bf(a1.w * inv1) << 16);
    o1.z = f2bf(b1.x * inv1) | ((unsigned)f2bf(b1.y * inv1) << 16);
    o1.w = f2bf(b1.z * inv1) | ((unsigned)f2bf(b1.w * inv1) << 16);
    *(uint4*)(kn + (size_t)pix0 * Dd + l * 8) = o0;
    *(uint4*)(kn + (size_t)(pix0 + 1) * Dd + l * 8) = o1;
}

// ---------- K1: corr with fused rubin bilinear (A in-register), norm folded post-MFMA ----------
__global__ __launch_bounds__(512, 4) void corr_block(const float* __restrict__ rub,
                                                     const unsigned short* __restrict__ kn,
                                                     const float* __restrict__ log_temp,
                                                     unsigned short* __restrict__ xb,
                                                     float* __restrict__ out) {
    // token stage: 60 slots (6 rows x 10 cols) x 260 f32 = 62400 B.
    // K halo (46080 B) and sC (33280 B) alias this region afterward.
    __shared__ __align__(16) char smem[62400];
    float* stok = (float*)smem;
    unsigned* sC = (unsigned*)smem;
    int tid = threadIdx.x;
    int wid = tid >> 6, lane = tid & 63, l15 = lane & 15, quad = lane >> 4;
    int blk = blockIdx.x;                    // 512 = 4 b x 16 ty x 8 tx
    int b = blk >> 7, rem = blk & 127;
    int y0 = (rem >> 3) << 3, x0 = (rem & 7) << 4;
    int y = y0 + wid;
    int ry0 = (y0 >> 1) - 1, cx0 = (x0 >> 1) - 1;

    // ---- stage 60 rubin tokens (clamped), 3840 granules, 8 rounds ----
#pragma unroll
    for (int i = 0; i < 8; i++) {
        int g = i * 512 + tid;
        if (g < 3840) {
            int t = g >> 6, c = g & 63;
            int jy = t / 10, jxx = t - jy * 10;
            int gy = min(max(ry0 + jy, 0), 63);
            int gx = min(max(cx0 + jxx, 0), 63);
            *(float4*)&stok[t * 260 + c * 4] =
                *(const float4*)(rub + ((size_t)(b * 4096 + gy * 64 + gx)) * 256 + c * 4);
        }
    }

    // ---- K-halo staging descriptors + first-chunk kn prefetch (global, overlaps) ----
    int soff[5], dstf[5];
#pragma unroll
    for (int i = 0; i < 5; i++) {
        int g = i * 512 + tid;
        int px = g >> 3, sub = g & 7;
        int pxc = min(px, 307);
        int ry = pxc / 22, rx = pxc - ry * 22;
        int yy = min(max(y0 - 3 + ry, 0), 127);
        int xx = min(max(x0 - 3 + rx, 0), 127);
        soff[i] = ((b << 14) + yy * 128 + xx) * 256 + sub * 8;   // shorts
        dstf[i] = px * 144 + sub * 16;                            // bytes
    }
    int lpixoff[10];
#pragma unroll
    for (int f = 0; f < 10; f++) {
        int p = min(f * 16 + l15, 153);
        int pr = p / 22, pc = p - pr * 22;
        lpixoff[f] = ((wid + pr) * 22 + pc) * 144 + quad * 16;
    }
    uint4 st0 = *(const uint4*)(kn + soff[0]);
    uint4 st1 = *(const uint4*)(kn + soff[1]);
    uint4 st2 = *(const uint4*)(kn + soff[2]);
    uint4 st3 = *(const uint4*)(kn + soff[3]);
    uint4 st4 = *(const uint4*)(kn + soff[4]);

    __syncthreads();   // token stage visible

    // ---- in-register bilinear: pixel (y, x0+l15), 8 UNNORMALIZED A fragments ----
    s16x8 afr[8];
    float inv;
    {
        int xq = x0 + l15;
        float sy = 0.5f * y - 0.25f, sx = 0.5f * xq - 0.25f;
        float fyf = floorf(sy), fxf = floorf(sx);
        float fy = sy - fyf, fx = sx - fxf;
        int iy = (int)fyf - ry0, jx = (int)fxf - cx0;
        const float* tb = &stok[(iy * 10 + jx) * 260];
        float w00 = (1.f - fy) * (1.f - fx), w01 = (1.f - fy) * fx;
        float w10 = fy * (1.f - fx), w11 = fy * fx;
        float ss = 0.f;
#pragma unroll
        for (int j = 0; j < 8; j++) {
            int f0 = j * 16 + quad * 4;
            float4 A0 = *(const float4*)(tb + f0);
            float4 A1 = *(const float4*)(tb + 128 + f0);
            float4 B0 = *(const float4*)(tb + 260 + f0);
            float4 B1 = *(const float4*)(tb + 388 + f0);
            float4 C0 = *(const float4*)(tb + 2600 + f0);
            float4 C1 = *(const float4*)(tb + 2728 + f0);
            float4 D0 = *(const float4*)(tb + 2860 + f0);
            float4 D1 = *(const float4*)(tb + 2988 + f0);
            float v0 = w00 * A0.x + w01 * B0.x + w10 * C0.x + w11 * D0.x;
            float v1 = w00 * A0.y + w01 * B0.y + w10 * C0.y + w11 * D0.y;
            float v2 = w00 * A0.z + w01 * B0.z + w10 * C0.z + w11 * D0.z;
            float v3 = w00 * A0.w + w01 * B0.w + w10 * C0.w + w11 * D0.w;
            float v4 = w00 * A1.x + w01 * B1.x + w10 * C1.x + w11 * D1.x;
            float v5 = w00 * A1.y + w01 * B1.y + w10 * C1.y + w11 * D1.y;
            float v6 = w00 * A1.z + w01 * B1.z + w10 * C1.z + w11 * D1.z;
            float v7 = w00 * A1.w + w01 * B1.w + w10 * C1.w + w11 * D1.w;
            ss += v0 * v0 + v1 * v1 + v2 * v2 + v3 * v3 +
                  v4 * v4 + v5 * v5 + v6 * v6 + v7 * v7;
            unsigned short* fp = (unsigned short*)&afr[j];
            fp[0] = f2bf(v0); fp[1] = f2bf(v1); fp[2] = f2bf(v2); fp[3] = f2bf(v3);
            fp[4] = f2bf(v4); fp[5] = f2bf(v5); fp[6] = f2bf(v6); fp[7] = f2bf(v7);
        }
        ss += __shfl_xor(ss, 16, 64);
        ss += __shfl_xor(ss, 32, 64);
        inv = __builtin_amdgcn_rsqf(fmaxf(ss, 1e-24f));
    }

    f32x4 acc[10];
#pragma unroll
    for (int f = 0; f < 10; f++) acc[f] = (f32x4){0.f, 0.f, 0.f, 0.f};

    for (int c4 = 0; c4 < 4; c4++) {
        uint4 w0 = st0, w1 = st1, w2 = st2, w3 = st3, w4 = st4;
        if (c4 < 3) {
            int co = (c4 + 1) * 64;
            st0 = *(const uint4*)(kn + soff[0] + co);
            st1 = *(const uint4*)(kn + soff[1] + co);
            st2 = *(const uint4*)(kn + soff[2] + co);
            st3 = *(const uint4*)(kn + soff[3] + co);
            st4 = *(const uint4*)(kn + soff[4] + co);
        }
        __syncthreads();
        *(uint4*)(smem + dstf[0]) = w0;
        *(uint4*)(smem + dstf[1]) = w1;
        *(uint4*)(smem + dstf[2]) = w2;
        *(uint4*)(smem + dstf[3]) = w3;
        *(uint4*)(smem + dstf[4]) = w4;
        __syncthreads();
        s16x8 wa0 = afr[2 * c4], wa1 = afr[2 * c4 + 1];
#pragma unroll
        for (int f = 0; f < 10; f++) {
            s16x8 bf = *(const s16x8*)(smem + lpixoff[f]);
            acc[f] = __builtin_amdgcn_mfma_f32_16x16x32_bf16(wa0, bf, acc[f], 0, 0, 0);
        }
#pragma unroll
        for (int f = 0; f < 10; f++) {
            s16x8 bf = *(const s16x8*)(smem + lpixoff[f] + 64);
            acc[f] = __builtin_amdgcn_mfma_f32_16x16x32_bf16(wa1, bf, acc[f], 0, 0, 0);
        }
    }

    // fold the q-normalization into the accumulator (exact, linear)
    float invm[4];
#pragma unroll
    for (int i = 0; i < 4; i++) invm[i] = __shfl(inv, quad * 4 + i, 16);
#pragma unroll
    for (int f = 0; f < 10; f++) {
#pragma unroll
        for (int i = 0; i < 4; i++) acc[f][i] *= invm[i];
    }

    __syncthreads();   // halo dead; smem becomes sC

    // zero pad-channels 52..63 of the transpose tile
#pragma unroll
    for (int i = 0; i < 3; i++) {
        int g = i * 512 + tid;               // 1536 exactly
        int px = g / 12, ch = 52 + g - (g / 12) * 12;
        sC[px * 65 + ch] = 0u;
    }

    float inv_temp = expf(-log_temp[0]);
    float vmax[4] = {-1e30f, -1e30f, -1e30f, -1e30f};
#pragma unroll
    for (int f = 0; f < 10; f++) {
        int n = f * 16 + l15;
        if (n <= 153) {
            int dy = n / 22 - 3;
            int rx = n - (dy + 3) * 22;
#pragma unroll
            for (int i = 0; i < 4; i++) {
                int m = quad * 4 + i;
                int dx = rx - m - 3;
                if ((unsigned)(dx + 3) <= 6u) vmax[i] = fmaxf(vmax[i], acc[f][i]);
            }
        }
    }
#pragma unroll
    for (int o = 1; o <= 8; o <<= 1) {
#pragma unroll
        for (int i = 0; i < 4; i++) vmax[i] = fmaxf(vmax[i], __shfl_xor(vmax[i], o, 64));
    }
    float se[4] = {0, 0, 0, 0}, sey[4] = {0, 0, 0, 0}, sex[4] = {0, 0, 0, 0}, emax[4] = {0, 0, 0, 0};
#pragma unroll
    for (int f = 0; f < 10; f++) {
        int n = f * 16 + l15;
        if (n <= 153) {
            int dy = n / 22 - 3;
            int rx = n - (dy + 3) * 22;
#pragma unroll
            for (int i = 0; i < 4; i++) {
                int m = quad * 4 + i;
                int dx = rx - m - 3;
                if ((unsigned)(dx + 3) <= 6u) {
                    float v = acc[f][i];
                    float e = expf((v - vmax[i]) * inv_temp);
                    se[i] += e;
                    sey[i] += e * (float)dy;
                    sex[i] += e * (float)dx;
                    emax[i] = fmaxf(emax[i], e);
                    sC[(wid * 16 + m) * 65 + 2 + (dy + 3) * 7 + (dx + 3)] = (unsigned)f2bf(v);
                }
            }
        }
    }
#pragma unroll
    for (int o = 1; o <= 8; o <<= 1) {
#pragma unroll
        for (int i = 0; i < 4; i++) {
            se[i] += __shfl_xor(se[i], o, 64);
            sey[i] += __shfl_xor(sey[i], o, 64);
            sex[i] += __shfl_xor(sex[i], o, 64);
            emax[i] = fmaxf(emax[i], __shfl_xor(emax[i], o, 64));
        }
    }
    if (l15 == 0) {
#pragma unroll
        for (int i = 0; i < 4; i++) {
            int m = quad * 4 + i;
            float inv_se = 1.0f / se[i];
            float dyv = sey[i] * inv_se, dxv = sex[i] * inv_se, conf = emax[i] * inv_se;
            int px = wid * 16 + m;
            sC[px * 65 + 0] = (unsigned)f2bf(dyv);
            sC[px * 65 + 1] = (unsigned)f2bf(dxv);
            sC[px * 65 + 51] = (unsigned)f2bf(conf);
            float* op = out + (size_t)b * 5 * HW + y * 128 + x0 + m;
            op[2 * HW] = dyv; op[3 * HW] = dxv; op[4 * HW] = conf;
        }
    }
    __syncthreads();
    // packed coalesced writeout: 128 px x 64 ch bf16 = 1024 uint4
#pragma unroll
    for (int i = 0; i < 2; i++) {
        int t2 = i * 512 + tid;
        int px = t2 >> 3, seg = t2 & 7;
        const unsigned* sp = sC + px * 65 + seg * 8;
        uint4 o;
        o.x = sp[0] | (sp[1] << 16);
        o.y = sp[2] | (sp[3] << 16);
        o.z = sp[4] | (sp[5] << 16);
        o.w = sp[6] | (sp[7] << 16);
        unsigned short* dst = xb + ((size_t)(b * WP + y0 + (px >> 4) + 2) * WP + x0 + (px & 15) + 2) * 64 + seg * 8;
        *(uint4*)dst = o;
    }
}

// ---------- K2: conv1 (52->32, xb WP/2-ring in, h1 WP1/4-ring out) ----------
__global__ __launch_bounds__(512, 4) void conv1_tile(const unsigned short* __restrict__ in,
                                                     const unsigned short* __restrict__ wb,
                                                     const float* __restrict__ bias,
                                                     unsigned short* __restrict__ outp) {
    constexpr int KS = 2, OC = 32, ICP = 64;
    constexpr int NF = OC / 16;
    constexpr int ABYTES = 240 * 64;            // 12x20 halo, 32ch chunk
    constexpr int WROWS = 25 * OC;
    constexpr int WGRAN = WROWS * 4;
    __shared__ char smem[ABYTES + WROWS * 64];
    int tid = threadIdx.x;
    int wv = tid >> 6, lane = tid & 63, l15 = lane & 15, quad = lane >> 4;
    int blk = blockIdx.x;
    int b = blk >> 7, rem = blk & 127;
    int ty = rem >> 3, tx = rem & 7;
    int y0 = ty * 8, x0 = tx * 16;

    f32x4 acc[NF];
#pragma unroll
    for (int g = 0; g < NF; g++) acc[g] = (f32x4){0.f, 0.f, 0.f, 0.f};

    for (int ks = 0; ks < KS; ks++) {
        __syncthreads();
#pragma unroll
        for (int i = 0; i < 2; i++) {
            int g = i * 512 + tid;
            if (g < 960) {
                int px = g >> 2, sub = g & 3;
                int r = px / 20, c = px - r * 20;
                *(uint4*)(smem + px * 64 + (((sub ^ (px >> 1)) & 3) << 4)) =
                    *(const uint4*)(in + ((size_t)(b * WP + y0 + r) * WP + x0 + c) * ICP + ks * 32 + sub * 8);
            }
        }
#pragma unroll
        for (int i = 0; i < (WGRAN + 511) / 512; i++) {
            int g = i * 512 + tid;
            if (g < WGRAN) {
                int nl = g >> 2, sub = g & 3;
                *(uint4*)(smem + ABYTES + nl * 64 + (((sub ^ (nl >> 1)) & 3) << 4)) =
                    *(const uint4*)(wb + (size_t)nl * ICP + ks * 32 + sub * 8);
            }
        }
        __syncthreads();
#pragma unroll
        for (int ky = 0; ky < 5; ky++) {
#pragma unroll
            for (int kx = 0; kx < 5; kx++) {
                int px = (wv + ky) * 20 + l15 + kx;
                s16x8 a = *(const s16x8*)(smem + px * 64 + (((quad ^ (px >> 1)) & 3) << 4));
#pragma unroll
                for (int g = 0; g < NF; g++) {
                    int row = (ky * 5 + kx) * OC + g * 16 + l15;
                    s16x8 bf = *(const s16x8*)(smem + ABYTES + row * 64 + (((quad ^ (row >> 1)) & 3) << 4));
                    acc[g] = __builtin_amdgcn_mfma_f32_16x16x32_bf16(a, bf, acc[g], 0, 0, 0);
                }
            }
        }
    }
    size_t orow = ((size_t)(b * WP1 + y0 + wv + 4) * WP1 + x0 + 4) * OC;
#pragma unroll
    for (int g = 0; g < NF; g++) {
        float bv = bias[g * 16 + l15];
#pragma unroll
        for (int r = 0; r < 4; r++) {
            int m = quad * 4 + r;
            float v = gelu_exact(acc[g][r] + bv);
            outp[orow + (size_t)m * OC + g * 16 + l15] = f2bf(v);
        }
    }
}

// ---------- K3: fused conv2 + final (h2 LDS-resident, halo recompute) ----------
__global__ __launch_bounds__(512, 4) void conv2_final(const unsigned short* __restrict__ h1,
                                                      const unsigned short* __restrict__ wb1,
                                                      const float* __restrict__ b1,
                                                      const unsigned short* __restrict__ wb2,
                                                      const float* __restrict__ b2,
                                                      float* __restrict__ out) {
    constexpr int H1B = 384 * 64;               // 16x24 h1 stage = 24576
    constexpr int WOFF = H1B;                   // W region, 13*32*64 = 26624 max
    constexpr int H2OFF = H1B + 26624;          // h2: 240*64 = 15360 -> total 66560
    __shared__ __align__(16) char smem[66560];
    int tid = threadIdx.x;
    int wv = tid >> 6, lane = tid & 63, l15 = lane & 15, quad = lane >> 4;
    int blk = blockIdx.x;
    int b = blk >> 7, rem = blk & 127;
    int ty = rem >> 3, tx = rem & 7;
    int y0 = ty * 8, x0 = tx * 16;

    // per-lane conv2 unit geometry: unit u = s*8+wv (u<15), A px p = u*16+l15
    int p0u = wv * 16 + l15;
    int p1u = (8 + wv) * 16 + l15;
    int r0 = p0u / 20, c0 = p0u - r0 * 20;
    int r1 = p1u / 20, c1 = p1u - r1 * 20;
    bool has1 = ((8 + wv) < 15);

    // stage h1 16x24: 1536 granules, 3 rounds exactly
#pragma unroll
    for (int i = 0; i < 3; i++) {
        int g = i * 512 + tid;
        int px = g >> 2, sub = g & 3;
        int r = px / 24, c = px - r * 24;
        *(uint4*)(smem + px * 64 + (((sub ^ (px >> 1)) & 3) << 4)) =
            *(const uint4*)(h1 + ((size_t)(b * WP1 + y0 + r) * WP1 + x0 + c) * 32 + sub * 8);
    }
    // stage W1 taps 0..12: 416 rows = 1664 granules
#pragma unroll
    for (int i = 0; i < 4; i++) {
        int g = i * 512 + tid;
        if (g < 1664) {
            int nl = g >> 2, sub = g & 3;
            *(uint4*)(smem + WOFF + nl * 64 + (((sub ^ (nl >> 1)) & 3) << 4)) =
                *(const uint4*)(wb1 + (size_t)nl * 32 + sub * 8);
        }
    }
    __syncthreads();

    f32x4 acc2[2][2];
#pragma unroll
    for (int s = 0; s < 2; s++) { acc2[s][0] = (f32x4){0,0,0,0}; acc2[s][1] = (f32x4){0,0,0,0}; }

    // conv2 taps 0..12
    for (int t = 0; t < 13; t++) {
        int tap = t, ky = tap / 5, kx = tap - ky * 5;
        int lr0 = t * 32 + l15, lr1 = t * 32 + 16 + l15;
        s16x8 wf0 = *(const s16x8*)(smem + WOFF + lr0 * 64 + (((quad ^ (lr0 >> 1)) & 3) << 4));
        s16x8 wf1 = *(const s16x8*)(smem + WOFF + lr1 * 64 + (((quad ^ (lr1 >> 1)) & 3) << 4));
        {
            int px = (r0 + ky) * 24 + c0 + kx;
            s16x8 a = *(const s16x8*)(smem + px * 64 + (((quad ^ (px >> 1)) & 3) << 4));
            acc2[0][0] = __builtin_amdgcn_mfma_f32_16x16x32_bf16(a, wf0, acc2[0][0], 0, 0, 0);
            acc2[0][1] = __builtin_amdgcn_mfma_f32_16x16x32_bf16(a, wf1, acc2[0][1], 0, 0, 0);
        }
        if (has1) {
            int px = (r1 + ky) * 24 + c1 + kx;
            s16x8 a = *(const s16x8*)(smem + px * 64 + (((quad ^ (px >> 1)) & 3) << 4));
            acc2[1][0] = __builtin_amdgcn_mfma_f32_16x16x32_bf16(a, wf0, acc2[1][0], 0, 0, 0);
            acc2[1][1] = __builtin_amdgcn_mfma_f32_16x16x32_bf16(a, wf1, acc2[1][1], 0, 0, 0);
        }
    }
    __syncthreads();
    // stage W1 taps 13..24: 384 rows = 1536 granules
#pragma unroll
    for (int i = 0; i < 3; i++) {
        int g = i * 512 + tid;
        int nl = g >> 2, sub = g & 3;
        *(uint4*)(smem + WOFF + nl * 64 + (((sub ^ (nl >> 1)) & 3) << 4)) =
            *(const uint4*)(wb1 + (size_t)(416 + nl) * 32 + sub * 8);
    }
    __syncthreads();
    // conv2 taps 13..24
    for (int t = 0; t < 12; t++) {
        int tap = 13 + t, ky = tap / 5, kx = tap - ky * 5;
        int lr0 = t * 32 + l15, lr1 = t * 32 + 16 + l15;
        s16x8 wf0 = *(const s16x8*)(smem + WOFF + lr0 * 64 + (((quad ^ (lr0 >> 1)) & 3) << 4));
        s16x8 wf1 = *(const s16x8*)(smem + WOFF + lr1 * 64 + (((quad ^ (lr1 >> 1)) & 3) << 4));
        {
            int px = (r0 + ky) * 24 + c0 + kx;
            s16x8 a = *(const s16x8*)(smem + px * 64 + (((quad ^ (px >> 1)) & 3) << 4));
            acc2[0][0] = __builtin_amdgcn_mfma_f32_16x16x32_bf16(a, wf0, acc2[0][0], 0, 0, 0);
            acc2[0][1] = __builtin_amdgcn_mfma_f32_16x16x32_bf16(a, wf1, acc2[0][1], 0, 0, 0);
        }
        if (has1) {
            int px = (r1 + ky) * 24 + c1 + kx;
            s16x8 a = *(const s16x8*)(smem + px * 64 + (((quad ^ (px >> 1)) & 3) << 4));
            acc2[1][0] = __builtin_amdgcn_mfma_f32_16x16x32_bf16(a, wf0, acc2[1][0], 0, 0, 0);
            acc2[1][1] = __builtin_amdgcn_mfma_f32_16x16x32_bf16(a, wf1, acc2[1][1], 0, 0, 0);
        }
    }
    // write h2 tile (bias + gelu, zero out-of-image = SAME-pad for final)
#pragma unroll
    for (int s = 0; s < 2; s++) {
        int u = s * 8 + wv;
        if (u < 15) {
#pragma unroll
            for (int g2 = 0; g2 < 2; g2++) {
                float bvv = b1[g2 * 16 + l15];
                int n = g2 * 16 + l15, gran = n >> 3;
#pragma unroll
                for (int rr = 0; rr < 4; rr++) {
                    int p = u * 16 + quad * 4 + rr;
                    int r2 = p / 20, c2 = p - r2 * 20;
                    int gy = y0 - 2 + r2, gx = x0 - 2 + c2;
                    float v = gelu_exact(acc2[s][g2][rr] + bvv);
                    unsigned short o = ((unsigned)gy < 128u && (unsigned)gx < 128u)
                                           ? f2bf(v) : (unsigned short)0;
                    *(unsigned short*)(smem + H2OFF + p * 64 +
                                       (((gran ^ (p >> 1)) & 3) << 4) + (n & 7) * 2) = o;
                }
            }
        }
    }
    __syncthreads();   // conv2 W reads done + h2 visible
    // stage W2: 400 rows = 1600 granules
#pragma unroll
    for (int i = 0; i < 4; i++) {
        int g = i * 512 + tid;
        if (g < 1600) {
            int nl = g >> 2, sub = g & 3;
            *(uint4*)(smem + WOFF + nl * 64 + (((sub ^ (nl >> 1)) & 3) << 4)) =
                *(const uint4*)(wb2 + (size_t)nl * 32 + sub * 8);
        }
    }
    __syncthreads();
    // final conv: wave = out row wv, cols l15
    f32x4 acc3 = (f32x4){0.f, 0.f, 0.f, 0.f};
    for (int t = 0; t < 25; t++) {
        int ky = t / 5, kx = t - ky * 5;
        int p3 = (wv + ky) * 20 + l15 + kx;
        s16x8 a = *(const s16x8*)(smem + H2OFF + p3 * 64 + (((quad ^ (p3 >> 1)) & 3) << 4));
        int lr = t * 16 + l15;
        s16x8 bf = *(const s16x8*)(smem + WOFF + lr * 64 + (((quad ^ (lr >> 1)) & 3) << 4));
        acc3 = __builtin_amdgcn_mfma_f32_16x16x32_bf16(a, bf, acc3, 0, 0, 0);
    }
    if (l15 < 2) {
        float bv = b2[l15];
#pragma unroll
        for (int rr = 0; rr < 4; rr++) {
            int m = quad * 4 + rr;
            size_t p5 = (size_t)b * 5 * HW + (y0 + wv) * Ww + x0 + m;
            float a = acc3[rr] + bv;
            if (l15 == 0) {
                float dyv = out[p5 + 2 * HW];
                out[p5 + HW] = (dyv + a) * 1.6f;   // ddec
            } else {
                float dxv = out[p5 + 3 * HW];
                out[p5] = (dxv + a) * 1.6f;        // dra
            }
        }
    }
}

extern "C" void kernel_launch(void* const* d_in, const int* in_sizes, int n_in,
                              void* d_out, int out_size, void* d_ws, size_t ws_size,
                              hipStream_t stream) {
    const float* rub = (const float*)d_in[0];
    const float* vis = (const float*)d_in[1];
    const float* w0 = (const float*)d_in[2];
    const float* b0 = (const float*)d_in[3];
    const float* w1 = (const float*)d_in[4];
    const float* b1 = (const float*)d_in[5];
    const float* w2 = (const float*)d_in[6];
    const float* b2 = (const float*)d_in[7];
    const float* log_temp = (const float*)d_in[8];
    float* out = (float*)d_out;

    char* ws = (char*)d_ws;
    size_t off = 0;
    const size_t PADPIX = (size_t)Bb * WP * WP;      // 69,696 (xb)
    const size_t PADPIX1 = (size_t)Bb * WP1 * WP1;   // 73,984 (h1)
    unsigned short* kn = (unsigned short*)(ws + off); off += (size_t)NPIX * Dd * 2;
    unsigned short* xbp = (unsigned short*)(ws + off); off += PADPIX * 64 * 2;
    unsigned short* h1p = (unsigned short*)(ws + off); off += PADPIX1 * 32 * 2;
    unsigned short* wb0 = (unsigned short*)(ws + off); off += 51200 * 2;
    unsigned short* wb1 = (unsigned short*)(ws + off); off += 25600 * 2;
    unsigned short* wb2 = (unsigned short*)(ws + off); off += 12800 * 2;

    setup_norm<<<4708, 256, 0, stream>>>(w0, w1, w2, wb0, wb1, wb2,
                                         xbp, h1p, vis, kn);
    corr_block<<<512, 512, 0, stream>>>(rub, kn, log_temp, xbp, out);
    conv1_tile<<<512, 512, 0, stream>>>(xbp, wb0, b0, h1p);
    conv2_final<<<512, 512, 0, stream>>>(h1p, wb1, b1, wb2, b2, out);
}

// Round 10
// 194.547 us; speedup vs baseline: 1.1768x; 1.1768x over previous
//
#include <hip/hip_runtime.h>
#include <math.h>

#define Hh 128
#define Ww 128
#define Dd 256
#define Bb 4
#define HW (Hh*Ww)        // 16384
#define NPIX (Bb*HW)      // 65536
#define WP 132            // xb padded width/height (2-px zero ring)
#define WP1 136           // h1 padded width/height (4-px zero ring)

typedef __attribute__((ext_vector_type(8))) short s16x8;   // 8 bf16 (4 VGPRs)
typedef __attribute__((ext_vector_type(4))) float f32x4;

__device__ __forceinline__ unsigned short f2bf(float f) {
    unsigned u = __float_as_uint(f);
    u += 0x7FFF + ((u >> 16) & 1);
    return (unsigned short)(u >> 16);
}

__device__ __forceinline__ float gelu_exact(float v) {
    return 0.5f * v * (1.0f + erff(v * 0.70710678118654752f));
}

// ring pixel i in [0,1040) -> (y,x) on the 2-px border of a 132x132 image
__device__ __forceinline__ void ring_yx(int i, int& y, int& x) {
    if (i < 264) { y = i / 132; x = i - y * 132; }
    else if (i < 528) { int j = i - 264; int r = j / 132; y = 130 + r; x = j - r * 132; }
    else { int j = i - 528; y = 2 + (j >> 2); int m = j & 3; x = (m < 2) ? m : 128 + m; }
}

// ring pixel i in [0,2112) -> (y,x) on the 4-px border of a 136x136 image
__device__ __forceinline__ void ring4_yx(int i, int& y, int& x) {
    if (i < 544) { y = i / 136; x = i - y * 136; }
    else if (i < 1088) { int j = i - 544; int r = j / 136; y = 132 + r; x = j - r * 136; }
    else { int j = i - 1088; y = 4 + (j >> 3); int m = j & 7; x = (m < 4) ? m : 128 + m; }
}

// ---------- K0: ring zeros + weight transpose + vis norm + rubin bilinear norm ----------
// blocks 0..611    : xb ring (33280) + h1 ring4 (33792) + weights (89600)
// blocks 612..4707 : vis -> kn (16-lane group = 1 px)
// blocks 4708..5731: rubin bilinear -> qn via LDS-staged 6x6 token tile
__global__ __launch_bounds__(256) void setup_norm(const float* __restrict__ w0,
                                                  const float* __restrict__ w1,
                                                  const float* __restrict__ w2,
                                                  unsigned short* __restrict__ wb0,
                                                  unsigned short* __restrict__ wb1,
                                                  unsigned short* __restrict__ wb2,
                                                  unsigned short* __restrict__ xbp,
                                                  unsigned short* __restrict__ h1p,
                                                  const float* __restrict__ vis,
                                                  const float* __restrict__ rub,
                                                  unsigned short* __restrict__ kn,
                                                  unsigned short* __restrict__ qn) {
    __shared__ float stok[36 * 260];
    int tid = threadIdx.x;
    int blk = blockIdx.x;
    if (blk < 612) {
        int t = blk * 256 + tid;
        uint4 z = (uint4){0, 0, 0, 0};
        if (t < 33280) {
            int img = t / 8320; int r = t - img * 8320; int px = r >> 3, g = r & 7;
            int y, x; ring_yx(px, y, x);
            *(uint4*)(xbp + ((size_t)(img * WP + y) * WP + x) * 64 + g * 8) = z;
            return;
        }
        if (t < 67072) {
            int u2 = t - 33280;
            int img = u2 / 8448; int r = u2 - img * 8448; int px = r >> 2, g = r & 3;
            int y, x; ring4_yx(px, y, x);
            *(uint4*)(h1p + ((size_t)(img * WP1 + y) * WP1 + x) * 32 + g * 8) = z;
            return;
        }
        int u = t - 67072;
        if (u < 51200) {
            int tap = u >> 11; int r = u & 2047; int n = r >> 6; int k = r & 63;
            wb0[u] = (k < 52) ? f2bf(w0[n * 1300 + k * 25 + tap]) : (unsigned short)0;
        } else if (u < 76800) {
            int v = u - 51200; int tap = v >> 10; int r = v & 1023; int n = r >> 5; int k = r & 31;
            wb1[v] = f2bf(w1[n * 800 + k * 25 + tap]);
        } else if (u < 89600) {
            int v = u - 76800; int tap = v >> 9; int r = v & 511; int n = r >> 5; int k = r & 31;
            wb2[v] = (n < 2) ? f2bf(w2[n * 800 + k * 25 + tap]) : (unsigned short)0;
        }
        return;
    }
    int nb = blk - 612;
    int g16 = tid >> 4, l = tid & 15;
    if (nb < 4096) {
        int pix = nb * 16 + g16;
        const float* base = vis + (size_t)pix * Dd + l * 4;
        float4 v[4];
#pragma unroll
        for (int i = 0; i < 4; i++) v[i] = *(const float4*)(base + i * 64);
        float ss = 0.f;
#pragma unroll
        for (int i = 0; i < 4; i++)
            ss += v[i].x * v[i].x + v[i].y * v[i].y + v[i].z * v[i].z + v[i].w * v[i].w;
#pragma unroll
        for (int o = 1; o <= 8; o <<= 1) ss += __shfl_xor(ss, o, 64);
        float inv = __builtin_amdgcn_rsqf(fmaxf(ss, 1e-24f));
        unsigned short* op = kn + (size_t)pix * Dd + l * 4;
#pragma unroll
        for (int i = 0; i < 4; i++) {
            ushort4 o4;
            o4.x = f2bf(v[i].x * inv); o4.y = f2bf(v[i].y * inv);
            o4.z = f2bf(v[i].z * inv); o4.w = f2bf(v[i].w * inv);
            *(ushort4*)(op + i * 64) = o4;
        }
    } else {
        int blk2 = nb - 4096;                // 1024 tiles of 8x8 output px
        int b = blk2 >> 8;
        int rem = blk2 & 255;
        int ty = rem >> 4, tx = rem & 15;
        int oy0 = ty * 8, ox0 = tx * 8;
        int rb = ty * 4 - 1, cb = tx * 4 - 1;    // token window base (6x6)
#pragma unroll
        for (int i = 0; i < 9; i++) {
            int g = i * 256 + tid;               // 2304 granules exactly
            int t = g >> 6, c = g & 63;
            int jy = t / 6, jx = t - jy * 6;
            int gy = min(max(rb + jy, 0), 63);
            int gx = min(max(cb + jx, 0), 63);
            *(float4*)&stok[t * 260 + c * 4] =
                *(const float4*)(rub + ((size_t)(b * 4096 + gy * 64 + gx)) * 256 + c * 4);
        }
        __syncthreads();
        for (int k = 0; k < 4; k++) {
            int pp = g16 * 4 + k;
            int r = pp >> 3, c2 = pp & 7;
            int yo = oy0 + r, xo = ox0 + c2;
            float sy = 0.5f * yo - 0.25f, sx = 0.5f * xo - 0.25f;
            float fyf = floorf(sy), fxf = floorf(sx);
            float fy = sy - fyf, fx = sx - fxf;
            int jy0 = (int)fyf - rb, jx0 = (int)fxf - cb;   // in [0,4]
            const float* t00 = &stok[(jy0 * 6 + jx0) * 260 + l * 4];
            const float* t01 = t00 + 260;
            const float* t10 = t00 + 6 * 260;
            const float* t11 = t10 + 260;
            float w00 = (1.f - fy) * (1.f - fx), w01 = (1.f - fy) * fx;
            float w10 = fy * (1.f - fx), w11 = fy * fx;
            float4 bv[4];
            float ss = 0.f;
#pragma unroll
            for (int i = 0; i < 4; i++) {
                float4 a = *(const float4*)(t00 + i * 64);
                float4 b1 = *(const float4*)(t01 + i * 64);
                float4 c = *(const float4*)(t10 + i * 64);
                float4 d = *(const float4*)(t11 + i * 64);
                float4 v;
                v.x = w00 * a.x + w01 * b1.x + w10 * c.x + w11 * d.x;
                v.y = w00 * a.y + w01 * b1.y + w10 * c.y + w11 * d.y;
                v.z = w00 * a.z + w01 * b1.z + w10 * c.z + w11 * d.z;
                v.w = w00 * a.w + w01 * b1.w + w10 * c.w + w11 * d.w;
                bv[i] = v;
                ss += v.x * v.x + v.y * v.y + v.z * v.z + v.w * v.w;
            }
#pragma unroll
            for (int o = 1; o <= 8; o <<= 1) ss += __shfl_xor(ss, o, 64);
            float inv = __builtin_amdgcn_rsqf(fmaxf(ss, 1e-24f));
            size_t pix = (size_t)(b << 14) + yo * 128 + xo;
            unsigned short* op = qn + pix * Dd + l * 4;
#pragma unroll
            for (int i = 0; i < 4; i++) {
                ushort4 o4;
                o4.x = f2bf(bv[i].x * inv); o4.y = f2bf(bv[i].y * inv);
                o4.z = f2bf(bv[i].z * inv); o4.w = f2bf(bv[i].w * inv);
                *(ushort4*)(op + i * 64) = o4;
            }
        }
    }
}

// ---------- K1: 2D-tiled LDS corr + shuffle softmax + LDS-transposed vector writeout ----------
__global__ __launch_bounds__(512, 4) void corr_block(const unsigned short* __restrict__ qn,
                                                     const unsigned short* __restrict__ kn,
                                                     const float* __restrict__ log_temp,
                                                     unsigned short* __restrict__ xb,
                                                     float* __restrict__ out) {
    constexpr int ASMEM = 308 * 5 * 16;          // 24640 (14x22 halo)
    __shared__ char smem[ASMEM + 128 * 65 * 4];  // + 33280 output transpose tile
    unsigned* sC = (unsigned*)(smem + ASMEM);
    int tid = threadIdx.x;
    int wid = tid >> 6, lane = tid & 63, l15 = lane & 15, quad = lane >> 4;
    int blk = blockIdx.x;                    // 512 = 4 b x 16 ty x 8 tx
    int b = blk >> 7, rem = blk & 127;
    int y0 = (rem >> 3) << 3, x0 = (rem & 7) << 4;
    int y = y0 + wid;

    // zero pad-channels 52..63 of the transpose tile (ordered before use by loop syncs)
#pragma unroll
    for (int i = 0; i < 3; i++) {
        int g = i * 512 + tid;               // 1536 exactly
        int px = g / 12, ch = 52 + g - (g / 12) * 12;
        sC[px * 65 + ch] = 0u;
    }

    const unsigned short* src0; int dst0;
    const unsigned short* src1; int dst1;
    const unsigned short* src2; int dst2; bool hav2;
    {
        int g = tid;
        int px = g >> 2, sub = g & 3;
        int ry = px / 22, rx = px - ry * 22;
        int yy = min(max(y0 - 3 + ry, 0), 127);
        int xx = min(max(x0 - 3 + rx, 0), 127);
        src0 = kn + ((size_t)(b << 14) + yy * 128 + xx) * 256 + sub * 8;
        dst0 = (px * 5 + sub) * 16;
        g = 512 + tid;
        px = g >> 2; sub = g & 3;
        ry = px / 22; rx = px - ry * 22;
        yy = min(max(y0 - 3 + ry, 0), 127);
        xx = min(max(x0 - 3 + rx, 0), 127);
        src1 = kn + ((size_t)(b << 14) + yy * 128 + xx) * 256 + sub * 8;
        dst1 = (px * 5 + sub) * 16;
        g = 1024 + tid;
        hav2 = (g < 1232);
        int gc = hav2 ? g : 1231;
        px = gc >> 2; sub = gc & 3;
        ry = px / 22; rx = px - ry * 22;
        yy = min(max(y0 - 3 + ry, 0), 127);
        xx = min(max(x0 - 3 + rx, 0), 127);
        src2 = kn + ((size_t)(b << 14) + yy * 128 + xx) * 256 + sub * 8;
        dst2 = (px * 5 + sub) * 16;
    }
    int lpixoff[10];
#pragma unroll
    for (int f = 0; f < 10; f++) {
        int p = min(f * 16 + l15, 153);
        int pr = p / 22, pc = p - pr * 22;
        lpixoff[f] = (((wid + pr) * 22 + pc) * 5 + quad) * 16;
    }
    const unsigned short* aptr = qn + ((size_t)(b << 14) + y * 128 + x0 + l15) * 256 + quad * 8;

    f32x4 acc[10];
#pragma unroll
    for (int f = 0; f < 10; f++) acc[f] = (f32x4){0.f, 0.f, 0.f, 0.f};

    uint4 v0 = *(const uint4*)src0;
    uint4 v1 = *(const uint4*)src1;
    uint4 v2 = *(const uint4*)src2;
    s16x8 an = *(const s16x8*)aptr;
    for (int c = 0; c < 8; c++) {
        uint4 w0v = v0, w1v = v1, w2v = v2;
        s16x8 a = an;
        if (c < 7) {
            v0 = *(const uint4*)(src0 + (c + 1) * 32);
            v1 = *(const uint4*)(src1 + (c + 1) * 32);
            v2 = *(const uint4*)(src2 + (c + 1) * 32);
            an = *(const s16x8*)(aptr + (c + 1) * 32);
        }
        __syncthreads();
        *(uint4*)(smem + dst0) = w0v;
        *(uint4*)(smem + dst1) = w1v;
        if (hav2) *(uint4*)(smem + dst2) = w2v;
        __syncthreads();
#pragma unroll
        for (int f = 0; f < 10; f++) {
            s16x8 bf = *(const s16x8*)(smem + lpixoff[f]);
            acc[f] = __builtin_amdgcn_mfma_f32_16x16x32_bf16(a, bf, acc[f], 0, 0, 0);
        }
    }

    float inv_temp = expf(-log_temp[0]);
    float vmax[4] = {-1e30f, -1e30f, -1e30f, -1e30f};
#pragma unroll
    for (int f = 0; f < 10; f++) {
        int n = f * 16 + l15;
        if (n <= 153) {
            int dy = n / 22 - 3;
            int rx = n - (dy + 3) * 22;
#pragma unroll
            for (int i = 0; i < 4; i++) {
                int m = quad * 4 + i;
                int dx = rx - m - 3;
                if ((unsigned)(dx + 3) <= 6u) vmax[i] = fmaxf(vmax[i], acc[f][i]);
            }
        }
    }
#pragma unroll
    for (int o = 1; o <= 8; o <<= 1) {
#pragma unroll
        for (int i = 0; i < 4; i++) vmax[i] = fmaxf(vmax[i], __shfl_xor(vmax[i], o, 64));
    }
    float se[4] = {0, 0, 0, 0}, sey[4] = {0, 0, 0, 0}, sex[4] = {0, 0, 0, 0}, emax[4] = {0, 0, 0, 0};
#pragma unroll
    for (int f = 0; f < 10; f++) {
        int n = f * 16 + l15;
        if (n <= 153) {
            int dy = n / 22 - 3;
            int rx = n - (dy + 3) * 22;
#pragma unroll
            for (int i = 0; i < 4; i++) {
                int m = quad * 4 + i;
                int dx = rx - m - 3;
                if ((unsigned)(dx + 3) <= 6u) {
                    float v = acc[f][i];
                    float e = expf((v - vmax[i]) * inv_temp);
                    se[i] += e;
                    sey[i] += e * (float)dy;
                    sex[i] += e * (float)dx;
                    emax[i] = fmaxf(emax[i], e);
                    sC[(wid * 16 + m) * 65 + 2 + (dy + 3) * 7 + (dx + 3)] = (unsigned)f2bf(v);
                }
            }
        }
    }
#pragma unroll
    for (int o = 1; o <= 8; o <<= 1) {
#pragma unroll
        for (int i = 0; i < 4; i++) {
            se[i] += __shfl_xor(se[i], o, 64);
            sey[i] += __shfl_xor(sey[i], o, 64);
            sex[i] += __shfl_xor(sex[i], o, 64);
            emax[i] = fmaxf(emax[i], __shfl_xor(emax[i], o, 64));
        }
    }
    if (l15 == 0) {
#pragma unroll
        for (int i = 0; i < 4; i++) {
            int m = quad * 4 + i;
            float inv_se = 1.0f / se[i];
            float dyv = sey[i] * inv_se, dxv = sex[i] * inv_se, conf = emax[i] * inv_se;
            int px = wid * 16 + m;
            sC[px * 65 + 0] = (unsigned)f2bf(dyv);
            sC[px * 65 + 1] = (unsigned)f2bf(dxv);
            sC[px * 65 + 51] = (unsigned)f2bf(conf);
            float* op = out + (size_t)b * 5 * HW + y * 128 + x0 + m;
            op[2 * HW] = dyv; op[3 * HW] = dxv; op[4 * HW] = conf;
        }
    }
    __syncthreads();
    // packed coalesced writeout: 128 px x 64 ch bf16 = 1024 uint4
#pragma unroll
    for (int i = 0; i < 2; i++) {
        int t2 = i * 512 + tid;
        int px = t2 >> 3, seg = t2 & 7;
        const unsigned* sp = sC + px * 65 + seg * 8;
        uint4 o;
        o.x = sp[0] | (sp[1] << 16);
        o.y = sp[2] | (sp[3] << 16);
        o.z = sp[4] | (sp[5] << 16);
        o.w = sp[6] | (sp[7] << 16);
        unsigned short* dst = xb + ((size_t)(b * WP + y0 + (px >> 4) + 2) * WP + x0 + (px & 15) + 2) * 64 + seg * 8;
        *(uint4*)dst = o;
    }
}

// ---------- K2: conv1 (52->32, xb WP/2-ring in, h1 WP1/4-ring out) ----------
__global__ __launch_bounds__(512, 4) void conv1_tile(const unsigned short* __restrict__ in,
                                                     const unsigned short* __restrict__ wb,
                                                     const float* __restrict__ bias,
                                                     unsigned short* __restrict__ outp) {
    constexpr int KS = 2, OC = 32, ICP = 64;
    constexpr int NF = OC / 16;
    constexpr int ABYTES = 240 * 64;            // 12x20 halo, 32ch chunk
    constexpr int WROWS = 25 * OC;
    constexpr int WGRAN = WROWS * 4;
    __shared__ char smem[ABYTES + WROWS * 64];
    int tid = threadIdx.x;
    int wv = tid >> 6, lane = tid & 63, l15 = lane & 15, quad = lane >> 4;
    int blk = blockIdx.x;
    int b = blk >> 7, rem = blk & 127;
    int ty = rem >> 3, tx = rem & 7;
    int y0 = ty * 8, x0 = tx * 16;

    f32x4 acc[NF];
#pragma unroll
    for (int g = 0; g < NF; g++) acc[g] = (f32x4){0.f, 0.f, 0.f, 0.f};

    for (int ks = 0; ks < KS; ks++) {
        __syncthreads();
#pragma unroll
        for (int i = 0; i < 2; i++) {
            int g = i * 512 + tid;
            if (g < 960) {
                int px = g >> 2, sub = g & 3;
                int r = px / 20, c = px - r * 20;
                *(uint4*)(smem + px * 64 + (((sub ^ (px >> 1)) & 3) << 4)) =
                    *(const uint4*)(in + ((size_t)(b * WP + y0 + r) * WP + x0 + c) * ICP + ks * 32 + sub * 8);
            }
        }
#pragma unroll
        for (int i = 0; i < (WGRAN + 511) / 512; i++) {
            int g = i * 512 + tid;
            if (g < WGRAN) {
                int nl = g >> 2, sub = g & 3;
                *(uint4*)(smem + ABYTES + nl * 64 + (((sub ^ (nl >> 1)) & 3) << 4)) =
                    *(const uint4*)(wb + (size_t)nl * ICP + ks * 32 + sub * 8);
            }
        }
        __syncthreads();
#pragma unroll
        for (int ky = 0; ky < 5; ky++) {
#pragma unroll
            for (int kx = 0; kx < 5; kx++) {
                int px = (wv + ky) * 20 + l15 + kx;
                s16x8 a = *(const s16x8*)(smem + px * 64 + (((quad ^ (px >> 1)) & 3) << 4));
#pragma unroll
                for (int g = 0; g < NF; g++) {
                    int row = (ky * 5 + kx) * OC + g * 16 + l15;
                    s16x8 bf = *(const s16x8*)(smem + ABYTES + row * 64 + (((quad ^ (row >> 1)) & 3) << 4));
                    acc[g] = __builtin_amdgcn_mfma_f32_16x16x32_bf16(a, bf, acc[g], 0, 0, 0);
                }
            }
        }
    }
    size_t orow = ((size_t)(b * WP1 + y0 + wv + 4) * WP1 + x0 + 4) * OC;
#pragma unroll
    for (int g = 0; g < NF; g++) {
        float bv = bias[g * 16 + l15];
#pragma unroll
        for (int r = 0; r < 4; r++) {
            int m = quad * 4 + r;
            float v = gelu_exact(acc[g][r] + bv);
            outp[orow + (size_t)m * OC + g * 16 + l15] = f2bf(v);
        }
    }
}

// ---------- K3: fused conv2 + final (h2 LDS-resident, halo recompute) ----------
__global__ __launch_bounds__(512, 4) void conv2_final(const unsigned short* __restrict__ h1,
                                                      const unsigned short* __restrict__ wb1,
                                                      const float* __restrict__ b1,
                                                      const unsigned short* __restrict__ wb2,
                                                      const float* __restrict__ b2,
                                                      float* __restrict__ out) {
    constexpr int H1B = 384 * 64;               // 16x24 h1 stage = 24576
    constexpr int WOFF = H1B;                   // W region, 13*32*64 = 26624 max
    constexpr int H2OFF = H1B + 26624;          // h2: 240*64 = 15360 -> total 66560
    __shared__ __align__(16) char smem[66560];
    int tid = threadIdx.x;
    int wv = tid >> 6, lane = tid & 63, l15 = lane & 15, quad = lane >> 4;
    int blk = blockIdx.x;
    int b = blk >> 7, rem = blk & 127;
    int ty = rem >> 3, tx = rem & 7;
    int y0 = ty * 8, x0 = tx * 16;

    // per-lane conv2 unit geometry: unit u = s*8+wv (u<15), A px p = u*16+l15
    int p0u = wv * 16 + l15;
    int p1u = (8 + wv) * 16 + l15;
    int r0 = p0u / 20, c0 = p0u - r0 * 20;
    int r1 = p1u / 20, c1 = p1u - r1 * 20;
    bool has1 = ((8 + wv) < 15);

    // stage h1 16x24: 1536 granules, 3 rounds exactly
#pragma unroll
    for (int i = 0; i < 3; i++) {
        int g = i * 512 + tid;
        int px = g >> 2, sub = g & 3;
        int r = px / 24, c = px - r * 24;
        *(uint4*)(smem + px * 64 + (((sub ^ (px >> 1)) & 3) << 4)) =
            *(const uint4*)(h1 + ((size_t)(b * WP1 + y0 + r) * WP1 + x0 + c) * 32 + sub * 8);
    }
    // stage W1 taps 0..12: 416 rows = 1664 granules
#pragma unroll
    for (int i = 0; i < 4; i++) {
        int g = i * 512 + tid;
        if (g < 1664) {
            int nl = g >> 2, sub = g & 3;
            *(uint4*)(smem + WOFF + nl * 64 + (((sub ^ (nl >> 1)) & 3) << 4)) =
                *(const uint4*)(wb1 + (size_t)nl * 32 + sub * 8);
        }
    }
    __syncthreads();

    f32x4 acc2[2][2];
#pragma unroll
    for (int s = 0; s < 2; s++) { acc2[s][0] = (f32x4){0,0,0,0}; acc2[s][1] = (f32x4){0,0,0,0}; }

    // conv2 taps 0..12
    for (int t = 0; t < 13; t++) {
        int tap = t, ky = tap / 5, kx = tap - ky * 5;
        int lr0 = t * 32 + l15, lr1 = t * 32 + 16 + l15;
        s16x8 wf0 = *(const s16x8*)(smem + WOFF + lr0 * 64 + (((quad ^ (lr0 >> 1)) & 3) << 4));
        s16x8 wf1 = *(const s16x8*)(smem + WOFF + lr1 * 64 + (((quad ^ (lr1 >> 1)) & 3) << 4));
        {
            int px = (r0 + ky) * 24 + c0 + kx;
            s16x8 a = *(const s16x8*)(smem + px * 64 + (((quad ^ (px >> 1)) & 3) << 4));
            acc2[0][0] = __builtin_amdgcn_mfma_f32_16x16x32_bf16(a, wf0, acc2[0][0], 0, 0, 0);
            acc2[0][1] = __builtin_amdgcn_mfma_f32_16x16x32_bf16(a, wf1, acc2[0][1], 0, 0, 0);
        }
        if (has1) {
            int px = (r1 + ky) * 24 + c1 + kx;
            s16x8 a = *(const s16x8*)(smem + px * 64 + (((quad ^ (px >> 1)) & 3) << 4));
            acc2[1][0] = __builtin_amdgcn_mfma_f32_16x16x32_bf16(a, wf0, acc2[1][0], 0, 0, 0);
            acc2[1][1] = __builtin_amdgcn_mfma_f32_16x16x32_bf16(a, wf1, acc2[1][1], 0, 0, 0);
        }
    }
    __syncthreads();
    // stage W1 taps 13..24: 384 rows = 1536 granules
#pragma unroll
    for (int i = 0; i < 3; i++) {
        int g = i * 512 + tid;
        int nl = g >> 2, sub = g & 3;
        *(uint4*)(smem + WOFF + nl * 64 + (((sub ^ (nl >> 1)) & 3) << 4)) =
            *(const uint4*)(wb1 + (size_t)(416 + nl) * 32 + sub * 8);
    }
    __syncthreads();
    // conv2 taps 13..24
    for (int t = 0; t < 12; t++) {
        int tap = 13 + t, ky = tap / 5, kx = tap - ky * 5;
        int lr0 = t * 32 + l15, lr1 = t * 32 + 16 + l15;
        s16x8 wf0 = *(const s16x8*)(smem + WOFF + lr0 * 64 + (((quad ^ (lr0 >> 1)) & 3) << 4));
        s16x8 wf1 = *(const s16x8*)(smem + WOFF + lr1 * 64 + (((quad ^ (lr1 >> 1)) & 3) << 4));
        {
            int px = (r0 + ky) * 24 + c0 + kx;
            s16x8 a = *(const s16x8*)(smem + px * 64 + (((quad ^ (px >> 1)) & 3) << 4));
            acc2[0][0] = __builtin_amdgcn_mfma_f32_16x16x32_bf16(a, wf0, acc2[0][0], 0, 0, 0);
            acc2[0][1] = __builtin_amdgcn_mfma_f32_16x16x32_bf16(a, wf1, acc2[0][1], 0, 0, 0);
        }
        if (has1) {
            int px = (r1 + ky) * 24 + c1 + kx;
            s16x8 a = *(const s16x8*)(smem + px * 64 + (((quad ^ (px >> 1)) & 3) << 4));
            acc2[1][0] = __builtin_amdgcn_mfma_f32_16x16x32_bf16(a, wf0, acc2[1][0], 0, 0, 0);
            acc2[1][1] = __builtin_amdgcn_mfma_f32_16x16x32_bf16(a, wf1, acc2[1][1], 0, 0, 0);
        }
    }
    // write h2 tile (bias + gelu, zero out-of-image = SAME-pad for final)
#pragma unroll
    for (int s = 0; s < 2; s++) {
        int u = s * 8 + wv;
        if (u < 15) {
#pragma unroll
            for (int g2 = 0; g2 < 2; g2++) {
                float bvv = b1[g2 * 16 + l15];
                int n = g2 * 16 + l15, gran = n >> 3;
#pragma unroll
                for (int rr = 0; rr < 4; rr++) {
                    int p = u * 16 + quad * 4 + rr;
                    int r2 = p / 20, c2 = p - r2 * 20;
                    int gy = y0 - 2 + r2, gx = x0 - 2 + c2;
                    float v = gelu_exact(acc2[s][g2][rr] + bvv);
                    unsigned short o = ((unsigned)gy < 128u && (unsigned)gx < 128u)
                                           ? f2bf(v) : (unsigned short)0;
                    *(unsigned short*)(smem + H2OFF + p * 64 +
                                       (((gran ^ (p >> 1)) & 3) << 4) + (n & 7) * 2) = o;
                }
            }
        }
    }
    __syncthreads();   // conv2 W reads done + h2 visible
    // stage W2: 400 rows = 1600 granules
#pragma unroll
    for (int i = 0; i < 4; i++) {
        int g = i * 512 + tid;
        if (g < 1600) {
            int nl = g >> 2, sub = g & 3;
            *(uint4*)(smem + WOFF + nl * 64 + (((sub ^ (nl >> 1)) & 3) << 4)) =
                *(const uint4*)(wb2 + (size_t)nl * 32 + sub * 8);
        }
    }
    __syncthreads();
    // final conv: wave = out row wv, cols l15
    f32x4 acc3 = (f32x4){0.f, 0.f, 0.f, 0.f};
    for (int t = 0; t < 25; t++) {
        int ky = t / 5, kx = t - ky * 5;
        int p3 = (wv + ky) * 20 + l15 + kx;
        s16x8 a = *(const s16x8*)(smem + H2OFF + p3 * 64 + (((quad ^ (p3 >> 1)) & 3) << 4));
        int lr = t * 16 + l15;
        s16x8 bf = *(const s16x8*)(smem + WOFF + lr * 64 + (((quad ^ (lr >> 1)) & 3) << 4));
        acc3 = __builtin_amdgcn_mfma_f32_16x16x32_bf16(a, bf, acc3, 0, 0, 0);
    }
    if (l15 < 2) {
        float bv = b2[l15];
#pragma unroll
        for (int rr = 0; rr < 4; rr++) {
            int m = quad * 4 + rr;
            size_t p5 = (size_t)b * 5 * HW + (y0 + wv) * Ww + x0 + m;
            float a = acc3[rr] + bv;
            if (l15 == 0) {
                float dyv = out[p5 + 2 * HW];
                out[p5 + HW] = (dyv + a) * 1.6f;   // ddec
            } else {
                float dxv = out[p5 + 3 * HW];
                out[p5] = (dxv + a) * 1.6f;        // dra
            }
        }
    }
}

extern "C" void kernel_launch(void* const* d_in, const int* in_sizes, int n_in,
                              void* d_out, int out_size, void* d_ws, size_t ws_size,
                              hipStream_t stream) {
    const float* rub = (const float*)d_in[0];
    const float* vis = (const float*)d_in[1];
    const float* w0 = (const float*)d_in[2];
    const float* b0 = (const float*)d_in[3];
    const float* w1 = (const float*)d_in[4];
    const float* b1 = (const float*)d_in[5];
    const float* w2 = (const float*)d_in[6];
    const float* b2 = (const float*)d_in[7];
    const float* log_temp = (const float*)d_in[8];
    float* out = (float*)d_out;

    char* ws = (char*)d_ws;
    size_t off = 0;
    const size_t PADPIX = (size_t)Bb * WP * WP;      // 69,696 (xb)
    const size_t PADPIX1 = (size_t)Bb * WP1 * WP1;   // 73,984 (h1)
    unsigned short* kn = (unsigned short*)(ws + off); off += (size_t)NPIX * Dd * 2;
    unsigned short* qn = (unsigned short*)(ws + off); off += (size_t)NPIX * Dd * 2;
    unsigned short* xbp = (unsigned short*)(ws + off); off += PADPIX * 64 * 2;
    unsigned short* h1p = (unsigned short*)(ws + off); off += PADPIX1 * 32 * 2;
    unsigned short* wb0 = (unsigned short*)(ws + off); off += 51200 * 2;
    unsigned short* wb1 = (unsigned short*)(ws + off); off += 25600 * 2;
    unsigned short* wb2 = (unsigned short*)(ws + off); off += 12800 * 2;

    setup_norm<<<5732, 256, 0, stream>>>(w0, w1, w2, wb0, wb1, wb2,
                                         xbp, h1p, vis, rub, kn, qn);
    corr_block<<<512, 512, 0, stream>>>(qn, kn, log_temp, xbp, out);
    conv1_tile<<<512, 512, 0, stream>>>(xbp, wb0, b0, h1p);
    conv2_final<<<512, 512, 0, stream>>>(h1p, wb1, b1, wb2, b2, out);
}